// Round 6
// baseline (101.283 us; speedup 1.0000x reference)
//
#include <hip/hip_runtime.h>
#include <hip/hip_bf16.h>

#define NN 16384
#define NE 65536

typedef __attribute__((ext_vector_type(8))) short short8;
typedef __attribute__((ext_vector_type(4))) float f32x4;

using bf16 = __hip_bfloat16;

__device__ __forceinline__ float b2f(bf16 v){ return __bfloat162float(v); }
__device__ __forceinline__ bf16 f2b(float v){ return __float2bfloat16(v); }

// ================= k_setup: countfill + tap weights g | pack W =================
// blocks [0,256): edge e -> countfill + g ; [256,336): W pack
// (curs must be zeroed by a preceding memset node)
__global__ __launch_bounds__(256) void k_setup(
    const int* __restrict__ recv, const int* __restrict__ send,
    unsigned* __restrict__ curs, unsigned* __restrict__ csr,
    const float* __restrict__ rel, const float* __restrict__ a,
    const float* __restrict__ P1, const float* __restrict__ P2,
    const float* __restrict__ P3, const float* __restrict__ P4,
    float* __restrict__ g,
    const float* __restrict__ W1, const float* __restrict__ W2,
    const float* __restrict__ W3, const float* __restrict__ W4,
    bf16* __restrict__ Bp)
{
    int b = blockIdx.x;
    if(b < 256){
        int e = b*256 + threadIdx.x;
        // ---- countfill ----
        int rv = recv[e];
        unsigned pos = atomicAdd(&curs[rv], 1u);
        if(pos < 32u) csr[(unsigned)rv*32u + pos] = ((unsigned)e << 14) | (unsigned)send[e];
        // ---- tap softmax for all 4 convs ----
        float r0 = rel[e*3+0], r1 = rel[e*3+1], r2 = rel[e*3+2];
        float av = a[e];
        const float* Ps[4] = {P1,P2,P3,P4};
        for(int c=0;c<4;c++){
            const float* P = Ps[c];
            float lg[16]; float mx = -1e30f;
            #pragma unroll
            for(int k=0;k<16;k++){
                float v = r0*P[k] + r1*P[16+k] + r2*P[32+k];
                lg[k] = v; mx = fmaxf(mx, v);
            }
            float ssum = 0.f;
            #pragma unroll
            for(int k=0;k<16;k++){ lg[k] = __expf(lg[k]-mx); ssum += lg[k]; }
            float inv = av/ssum;
            float* go = &g[((size_t)c*NE + e)*16];
            #pragma unroll
            for(int j=0;j<4;j++){
                ((float4*)go)[j] = make_float4(lg[j*4]*inv, lg[j*4+1]*inv,
                                               lg[j*4+2]*inv, lg[j*4+3]*inv);
            }
        }
        return;
    }
    // ---- W pack into MFMA B-fragment order ----
    int t = (b-256)*256 + threadIdx.x;
    const float* W; int Cout; int base; int tl;
    if(t < 8192)      { W=W1; Cout=64; base=0;     tl=t; }
    else if(t < 12288){ W=W2; Cout=32; base=8192;  tl=t-8192; }
    else if(t < 16384){ W=W3; Cout=64; base=12288; tl=t-12288; }
    else              { W=W4; Cout=32; base=16384; tl=t-16384; }
    int l  = tl & 63;
    int NCT = Cout >> 4;
    int ct = (tl >> 6) % NCT;
    int ks = (tl >> 6) / NCT;
    int col = ct*16 + (l & 15);
    int k0  = ks*32 + ((l >> 4) & 3)*8;
    short8 v;
    #pragma unroll
    for(int j=0;j<8;j++){
        bf16 h = f2b(W[(size_t)(k0+j)*Cout + col]);
        v[j] = (short)*(unsigned short*)&h;
    }
    ((short8*)Bp)[base + tl] = v;
}

// ================= fused conv: 2 nodes/wave agg -> LDS -> MFMA -> epilogue ===
// Block: 1024 threads = 16 waves = 32 nodes (M-tile 32). Wave wv aggregates
// nodes nbase+2wv, nbase+2wv+1 with fully interleaved unrolled edge loads,
// writes bf16 rows to LDS (XOR swizzle), then waves 0..2*NCT-1 run the GEMM
// (row-tile rt, col-tile c, full K).
template<int CIN, int NCT, int MODE, bool CONCAT, typename OT>
__global__ __launch_bounds__(1024, 4) void k_conv(
    const void* __restrict__ fAv, const float* __restrict__ fBv,
    const float* __restrict__ g,
    const unsigned* __restrict__ csr, const unsigned* __restrict__ curs,
    const bf16* __restrict__ Bp, const float* __restrict__ bias,
    const float* __restrict__ bns, const float* __restrict__ bno,
    const float* __restrict__ bnm, const float* __restrict__ bnv,
    const float* __restrict__ x, const float* __restrict__ y,
    OT* __restrict__ out)
{
    constexpr int KD   = CIN*16;
    constexpr int ROWB = KD*2;
    __shared__ __align__(16) char sT[32*ROWB];
    int wv = threadIdx.x >> 6, lane = threadIdx.x & 63;
    int nbase = blockIdx.x*32;
    int nA = nbase + wv*2, nB = nA + 1;

    // ---------- aggregation (two nodes per wave, interleaved) ----------
    const float* fAf = (const float*)fAv;
    const bf16*  fAb = (const bf16*)fAv;
    const int i     = (CIN==64) ? lane : (lane & 31);
    const int kbase = (CIN==64) ? 0 : ((lane >> 5) * 8);
    unsigned cntA = curs[nA]; if(cntA > 32u) cntA = 32u;
    unsigned cntB = curs[nB]; if(cntB > 32u) cntB = 32u;
    const unsigned* crA = csr + (unsigned)nA*32u;
    const unsigned* crB = csr + (unsigned)nB*32u;
    uint4 a0 = ((const uint4*)crA)[0], a1 = ((const uint4*)crA)[1];
    uint4 b0 = ((const uint4*)crB)[0], b1 = ((const uint4*)crB)[1];
    unsigned uA[8] = {a0.x, a0.y, a0.z, a0.w, a1.x, a1.y, a1.z, a1.w};
    unsigned uB[8] = {b0.x, b0.y, b0.z, b0.w, b1.x, b1.y, b1.z, b1.w};

    constexpr int KPL = (CIN==64) ? 16 : 8;
    float accA[KPL], accB[KPL];
    #pragma unroll
    for(int r=0;r<KPL;r++){ accA[r] = 0.f; accB[r] = 0.f; }

    auto edge = [&](unsigned u, float* acc){
        int sid = (int)(u & 16383u);
        int eid = (int)(u >> 14);
        float fe;
        if(CONCAT){
            fe = (lane < 32) ? fAf[sid*32 + lane] : fBv[sid*32 + (lane-32)];
        } else {
            fe = b2f(fAb[sid*CIN + i]);
        }
        const float4* gp = (const float4*)&g[(size_t)eid*16 + kbase];
        if(CIN==64){
            float4 g0=gp[0], g1=gp[1], g2=gp[2], g3=gp[3];
            acc[0]  += g0.x*fe; acc[1]  += g0.y*fe; acc[2]  += g0.z*fe; acc[3]  += g0.w*fe;
            acc[4]  += g1.x*fe; acc[5]  += g1.y*fe; acc[6]  += g1.z*fe; acc[7]  += g1.w*fe;
            acc[8]  += g2.x*fe; acc[9]  += g2.y*fe; acc[10] += g2.z*fe; acc[11] += g2.w*fe;
            acc[12] += g3.x*fe; acc[13] += g3.y*fe; acc[14] += g3.z*fe; acc[15] += g3.w*fe;
        } else {
            float4 g0=gp[0], g1=gp[1];
            acc[0] += g0.x*fe; acc[1] += g0.y*fe; acc[2] += g0.z*fe; acc[3] += g0.w*fe;
            acc[4] += g1.x*fe; acc[5] += g1.y*fe; acc[6] += g1.z*fe; acc[7] += g1.w*fe;
        }
    };
    #pragma unroll
    for(int j=0;j<8;j++){
        if((unsigned)j < cntA) edge(uA[j], accA);
        if((unsigned)j < cntB) edge(uB[j], accB);
    }
    for(unsigned j=8; j<cntA; j++) edge(crA[j], accA);
    for(unsigned j=8; j<cntB; j++) edge(crB[j], accB);

    // ---------- LDS writes (swizzled), both rows ----------
    {
        int nlA = wv*2, nlB = wv*2+1;
        unsigned xA = (unsigned)((nlA & 7) << 4);
        unsigned xB = (unsigned)((nlB & 7) << 4);
        if(CIN==64){
            #pragma unroll
            for(int k=0;k<16;k++){
                unsigned off = (unsigned)(k*64 + lane)*2u;
                *(bf16*)(sT + (unsigned)nlA*ROWB + (off ^ xA)) = f2b(accA[k]);
                *(bf16*)(sT + (unsigned)nlB*ROWB + (off ^ xB)) = f2b(accB[k]);
            }
        } else {
            #pragma unroll
            for(int r=0;r<8;r++){
                unsigned off = (unsigned)((kbase+r)*32 + i)*2u;
                *(bf16*)(sT + (unsigned)nlA*ROWB + (off ^ xA)) = f2b(accA[r]);
                *(bf16*)(sT + (unsigned)nlB*ROWB + (off ^ xB)) = f2b(accB[r]);
            }
        }
    }
    __syncthreads();

    // ---------- GEMM from LDS (waves 0..2*NCT-1) ----------
    if(wv >= 2*NCT) return;
    int rt, c;
    if(NCT==4){ rt = wv >> 2; c = wv & 3; }
    else      { rt = wv >> 1; c = wv & 1; }
    int r = lane & 15, h = lane >> 4;
    const short8* Bp8 = (const short8*)Bp;
    f32x4 acc4 = (f32x4){0.f,0.f,0.f,0.f};
    unsigned xr = (unsigned)((r & 7) << 4);
    #pragma unroll 8
    for(int ks=0; ks<KD/32; ks++){
        unsigned ab = (unsigned)(rt*16 + r)*ROWB + (((unsigned)(ks*64 + h*16)) ^ xr);
        short8 af  = *(const short8*)(sT + ab);
        short8 bfr = Bp8[(ks*NCT + c)*64 + lane];
        acc4 = __builtin_amdgcn_mfma_f32_16x16x32_bf16(af, bfr, acc4, 0, 0, 0);
    }

    // ---------- epilogue ----------
    const int Cout = NCT*16;
    int col = c*16 + r;
    float inv = rsqrtf(bnv[col] + 1e-5f);
    float al  = bns[col] * inv;
    float be  = al*(bias[col] - bnm[col]) + bno[col];
    #pragma unroll
    for(int j=0;j<4;j++){
        int rr = nbase + rt*16 + h*4 + j;
        float v = al*acc4[j] + be;
        if(MODE==0){
            out[(size_t)rr*Cout + col] = (OT)fmaxf(v, 0.f);
        } else {
            float wei = 1.f/(1.f + __expf(-v));
            float xv = x[rr*32 + col];
            float yv = y[rr*32 + col];
            out[(size_t)rr*32 + col] = (OT)(2.f*xv*wei + 2.f*yv*(1.f - wei));
        }
    }
}

// ================= launch =================
extern "C" void kernel_launch(void* const* d_in, const int* in_sizes, int n_in,
                              void* d_out, int out_size, void* d_ws, size_t ws_size,
                              hipStream_t stream){
    const float* x   = (const float*)d_in[0];
    const float* y   = (const float*)d_in[1];
    const int* send  = (const int*)d_in[2];
    const int* recv  = (const int*)d_in[3];
    const float* rel = (const float*)d_in[4];
    const float* a   = (const float*)d_in[5];
    const float *W[4], *P[4], *bb[4], *bs[4], *bo[4], *bm[4], *bv[4];
    for(int i=0;i<4;i++){
        int base = 6 + i*7;
        W[i]  = (const float*)d_in[base+0];
        P[i]  = (const float*)d_in[base+1];
        bb[i] = (const float*)d_in[base+2];
        bs[i] = (const float*)d_in[base+3];
        bo[i] = (const float*)d_in[base+4];
        bm[i] = (const float*)d_in[base+5];
        bv[i] = (const float*)d_in[base+6];
    }
    char* w = (char*)d_ws;
    float*    g    = (float*)(w);                   // 16,777,216 B
    unsigned* curs = (unsigned*)(w + 16777216);     //     65,536 B
    unsigned* csr  = (unsigned*)(w + 16842752);     //  2,097,152 B
    bf16*     h1   = (bf16*)(w + 18939904);         //  2,097,152 B
    bf16*     xo   = (bf16*)(w + 21037056);         //  1,048,576 B
    bf16*     h3   = (bf16*)(w + 22085632);         //  2,097,152 B
    bf16*     Bp   = (bf16*)(w + 24182784);         //    327,680 B
    float*    outp = (float*)d_out;

    hipMemsetAsync(curs, 0, NN*sizeof(unsigned), stream);
    k_setup<<<336, 256, 0, stream>>>(recv, send, curs, csr, rel, a,
                                     P[0], P[1], P[2], P[3], g,
                                     W[0], W[1], W[2], W[3], Bp);

    // conv1: [x|y] -> h1 (BN+relu)
    (k_conv<64,4,0,true,bf16>)  <<<NN/32, 1024, 0, stream>>>(x, y, g + (size_t)0*NE*16, csr, curs,
        Bp + (size_t)0*8,     bb[0], bs[0], bo[0], bm[0], bv[0], nullptr, nullptr, h1);
    // conv2: h1 -> wei1 -> xo (AFF)
    (k_conv<64,2,1,false,bf16>) <<<NN/32, 1024, 0, stream>>>(h1, nullptr, g + (size_t)1*NE*16, csr, curs,
        Bp + (size_t)8192*8,  bb[1], bs[1], bo[1], bm[1], bv[1], x, y, xo);
    // conv3: xo -> h3 (BN+relu)
    (k_conv<32,4,0,false,bf16>) <<<NN/32, 1024, 0, stream>>>(xo, nullptr, g + (size_t)2*NE*16, csr, curs,
        Bp + (size_t)12288*8, bb[2], bs[2], bo[2], bm[2], bv[2], nullptr, nullptr, h3);
    // conv4: h3 -> wei2 -> out (AFF, f32)
    (k_conv<64,2,1,false,float>)<<<NN/32, 1024, 0, stream>>>(h3, nullptr, g + (size_t)3*NE*16, csr, curs,
        Bp + (size_t)16384*8, bb[3], bs[3], bo[3], bm[3], bv[3], x, y, outp);
}

// Round 7
// 99.705 us; speedup vs baseline: 1.0158x; 1.0158x over previous
//
#include <hip/hip_runtime.h>
#include <hip/hip_bf16.h>

#define NN 16384
#define NE 65536

typedef __attribute__((ext_vector_type(8))) short short8;
typedef __attribute__((ext_vector_type(4))) float f32x4;

using bf16 = __hip_bfloat16;

__device__ __forceinline__ float b2f(bf16 v){ return __bfloat162float(v); }
__device__ __forceinline__ bf16 f2b(float v){ return __float2bfloat16(v); }

// ================= k_setup =================
// blocks [0,256):   edge e -> countfill + tap softmax g (all 4 convs)
// blocks [256,336): W pack into MFMA B-fragment order
// blocks [336,464): build xyc[n][64] bf16 = [x[n] | y[n]]
// (curs zeroed by preceding memset node)
__global__ __launch_bounds__(256) void k_setup(
    const int* __restrict__ recv, const int* __restrict__ send,
    unsigned* __restrict__ curs, unsigned* __restrict__ csr,
    const float* __restrict__ rel, const float* __restrict__ a,
    const float* __restrict__ P1, const float* __restrict__ P2,
    const float* __restrict__ P3, const float* __restrict__ P4,
    float* __restrict__ g,
    const float* __restrict__ W1, const float* __restrict__ W2,
    const float* __restrict__ W3, const float* __restrict__ W4,
    bf16* __restrict__ Bp,
    const float* __restrict__ x, const float* __restrict__ y,
    bf16* __restrict__ xyc)
{
    int b = blockIdx.x;
    if(b < 256){
        int e = b*256 + threadIdx.x;
        int rv = recv[e];
        unsigned pos = atomicAdd(&curs[rv], 1u);
        if(pos < 32u) csr[(unsigned)rv*32u + pos] = ((unsigned)e << 14) | (unsigned)send[e];
        float r0 = rel[e*3+0], r1 = rel[e*3+1], r2 = rel[e*3+2];
        float av = a[e];
        const float* Ps[4] = {P1,P2,P3,P4};
        for(int c=0;c<4;c++){
            const float* P = Ps[c];
            float lg[16]; float mx = -1e30f;
            #pragma unroll
            for(int k=0;k<16;k++){
                float v = r0*P[k] + r1*P[16+k] + r2*P[32+k];
                lg[k] = v; mx = fmaxf(mx, v);
            }
            float ssum = 0.f;
            #pragma unroll
            for(int k=0;k<16;k++){ lg[k] = __expf(lg[k]-mx); ssum += lg[k]; }
            float inv = av/ssum;
            float* go = &g[((size_t)c*NE + e)*16];
            #pragma unroll
            for(int j=0;j<4;j++){
                ((float4*)go)[j] = make_float4(lg[j*4]*inv, lg[j*4+1]*inv,
                                               lg[j*4+2]*inv, lg[j*4+3]*inv);
            }
        }
        return;
    }
    if(b < 336){
        int t = (b-256)*256 + threadIdx.x;
        const float* W; int Cout; int base; int tl;
        if(t < 8192)      { W=W1; Cout=64; base=0;     tl=t; }
        else if(t < 12288){ W=W2; Cout=32; base=8192;  tl=t-8192; }
        else if(t < 16384){ W=W3; Cout=64; base=12288; tl=t-12288; }
        else              { W=W4; Cout=32; base=16384; tl=t-16384; }
        int l  = tl & 63;
        int NCT = Cout >> 4;
        int ct = (tl >> 6) % NCT;
        int ks = (tl >> 6) / NCT;
        int col = ct*16 + (l & 15);
        int k0  = ks*32 + ((l >> 4) & 3)*8;
        short8 v;
        #pragma unroll
        for(int j=0;j<8;j++){
            bf16 h = f2b(W[(size_t)(k0+j)*Cout + col]);
            v[j] = (short)*(unsigned short*)&h;
        }
        ((short8*)Bp)[base + tl] = v;
        return;
    }
    // ---- xyc: [x | y] rounded to bf16, row-major 64ch ----
    int t = (b-336)*256 + threadIdx.x;   // [0, 32768)
    int n = t >> 1, half = t & 1;
    const float* src = half ? (y + n*32) : (x + n*32);
    bf16* dst = xyc + (size_t)n*64 + half*32;
    #pragma unroll
    for(int j=0;j<4;j++){
        float4 v0 = ((const float4*)src)[2*j];
        float4 v1 = ((const float4*)src)[2*j+1];
        short8 o;
        bf16 h;
        h = f2b(v0.x); o[0]=(short)*(unsigned short*)&h;
        h = f2b(v0.y); o[1]=(short)*(unsigned short*)&h;
        h = f2b(v0.z); o[2]=(short)*(unsigned short*)&h;
        h = f2b(v0.w); o[3]=(short)*(unsigned short*)&h;
        h = f2b(v1.x); o[4]=(short)*(unsigned short*)&h;
        h = f2b(v1.y); o[5]=(short)*(unsigned short*)&h;
        h = f2b(v1.z); o[6]=(short)*(unsigned short*)&h;
        h = f2b(v1.w); o[7]=(short)*(unsigned short*)&h;
        ((short8*)dst)[j] = o;
    }
}

// ================= fused conv: 1 node/wave agg -> LDS -> MFMA -> epilogue ===
// Block: 1024 threads = 16 waves = 16 nodes. 12-deep unrolled predicated edge
// loop (tail serial, P(deg>12)~7e-4). __launch_bounds__(1024,8) forces
// VGPR<=64 -> 2 blocks/CU co-resident.
template<int CIN, int NCT, int MODE, typename OT>
__global__ __launch_bounds__(1024, 8) void k_conv(
    const bf16* __restrict__ fAb,
    const float* __restrict__ g,
    const unsigned* __restrict__ csr, const unsigned* __restrict__ curs,
    const bf16* __restrict__ Bp, const float* __restrict__ bias,
    const float* __restrict__ bns, const float* __restrict__ bno,
    const float* __restrict__ bnm, const float* __restrict__ bnv,
    const float* __restrict__ x, const float* __restrict__ y,
    OT* __restrict__ out)
{
    constexpr int KD   = CIN*16;
    constexpr int ROWB = KD*2;
    __shared__ __align__(16) char sT[16*ROWB];
    int wv = threadIdx.x >> 6, lane = threadIdx.x & 63;
    int nbase = blockIdx.x*16;
    int node  = nbase + wv;

    // ---------- aggregation (one node per wave) ----------
    const unsigned* crow = csr + (unsigned)node*32u;
    unsigned cnt = curs[node]; if(cnt > 32u) cnt = 32u;
    uint4 c0 = ((const uint4*)crow)[0];
    uint4 c1 = ((const uint4*)crow)[1];
    uint4 c2 = ((const uint4*)crow)[2];
    unsigned uu[12] = {c0.x,c0.y,c0.z,c0.w, c1.x,c1.y,c1.z,c1.w, c2.x,c2.y,c2.z,c2.w};

    const int i     = (CIN==64) ? lane : (lane & 31);
    const int kbase = (CIN==64) ? 0 : ((lane >> 5) * 8);
    constexpr int KPL = (CIN==64) ? 16 : 8;
    float acc[KPL];
    #pragma unroll
    for(int r=0;r<KPL;r++) acc[r] = 0.f;

    auto edge = [&](unsigned u){
        int sid = (int)(u & 16383u);
        int eid = (int)(u >> 14);
        float fe = b2f(fAb[sid*CIN + i]);
        const float4* gp = (const float4*)&g[(size_t)eid*16 + kbase];
        if(CIN==64){
            float4 g0=gp[0], g1=gp[1], g2=gp[2], g3=gp[3];
            acc[0]  += g0.x*fe; acc[1]  += g0.y*fe; acc[2]  += g0.z*fe; acc[3]  += g0.w*fe;
            acc[4]  += g1.x*fe; acc[5]  += g1.y*fe; acc[6]  += g1.z*fe; acc[7]  += g1.w*fe;
            acc[8]  += g2.x*fe; acc[9]  += g2.y*fe; acc[10] += g2.z*fe; acc[11] += g2.w*fe;
            acc[12] += g3.x*fe; acc[13] += g3.y*fe; acc[14] += g3.z*fe; acc[15] += g3.w*fe;
        } else {
            float4 g0=gp[0], g1=gp[1];
            acc[0] += g0.x*fe; acc[1] += g0.y*fe; acc[2] += g0.z*fe; acc[3] += g0.w*fe;
            acc[4] += g1.x*fe; acc[5] += g1.y*fe; acc[6] += g1.z*fe; acc[7] += g1.w*fe;
        }
    };
    #pragma unroll
    for(int j=0;j<12;j++){
        if((unsigned)j < cnt) edge(uu[j]);
    }
    for(unsigned j=12; j<cnt; j++) edge(crow[j]);

    // ---------- LDS write (swizzled) ----------
    unsigned xo_ = (unsigned)((wv & 7) << 4);
    if(CIN==64){
        #pragma unroll
        for(int k=0;k<16;k++){
            unsigned byte = (unsigned)wv*ROWB + ((((unsigned)(k*64 + lane))*2u) ^ xo_);
            *(bf16*)(sT + byte) = f2b(acc[k]);
        }
    } else {
        #pragma unroll
        for(int r=0;r<8;r++){
            unsigned byte = (unsigned)wv*ROWB + ((((unsigned)((kbase+r)*32 + i))*2u) ^ xo_);
            *(bf16*)(sT + byte) = f2b(acc[r]);
        }
    }
    __syncthreads();

    // ---------- GEMM from LDS (waves 0..NCT-1, full K) ----------
    if(wv >= NCT) return;
    int r = lane & 15, h = lane >> 4;
    int c = wv;
    const short8* Bp8 = (const short8*)Bp;
    f32x4 acc4 = (f32x4){0.f,0.f,0.f,0.f};
    unsigned xr = (unsigned)((r & 7) << 4);
    #pragma unroll 8
    for(int ks=0; ks<KD/32; ks++){
        unsigned ab = (unsigned)r*ROWB + (((unsigned)(ks*64 + h*16)) ^ xr);
        short8 af  = *(const short8*)(sT + ab);
        short8 bfr = Bp8[(ks*NCT + c)*64 + lane];
        acc4 = __builtin_amdgcn_mfma_f32_16x16x32_bf16(af, bfr, acc4, 0, 0, 0);
    }

    // ---------- epilogue ----------
    const int Cout = NCT*16;
    int col = c*16 + r;
    float inv = rsqrtf(bnv[col] + 1e-5f);
    float al  = bns[col] * inv;
    float be  = al*(bias[col] - bnm[col]) + bno[col];
    #pragma unroll
    for(int j=0;j<4;j++){
        int rr = nbase + h*4 + j;
        float v = al*acc4[j] + be;
        if(MODE==0){
            out[(size_t)rr*Cout + col] = (OT)fmaxf(v, 0.f);
        } else {
            float wei = 1.f/(1.f + __expf(-v));
            float xv = x[rr*32 + col];
            float yv = y[rr*32 + col];
            out[(size_t)rr*32 + col] = (OT)(2.f*xv*wei + 2.f*yv*(1.f - wei));
        }
    }
}

// ================= launch =================
extern "C" void kernel_launch(void* const* d_in, const int* in_sizes, int n_in,
                              void* d_out, int out_size, void* d_ws, size_t ws_size,
                              hipStream_t stream){
    const float* x   = (const float*)d_in[0];
    const float* y   = (const float*)d_in[1];
    const int* send  = (const int*)d_in[2];
    const int* recv  = (const int*)d_in[3];
    const float* rel = (const float*)d_in[4];
    const float* a   = (const float*)d_in[5];
    const float *W[4], *P[4], *bb[4], *bs[4], *bo[4], *bm[4], *bv[4];
    for(int i=0;i<4;i++){
        int base = 6 + i*7;
        W[i]  = (const float*)d_in[base+0];
        P[i]  = (const float*)d_in[base+1];
        bb[i] = (const float*)d_in[base+2];
        bs[i] = (const float*)d_in[base+3];
        bo[i] = (const float*)d_in[base+4];
        bm[i] = (const float*)d_in[base+5];
        bv[i] = (const float*)d_in[base+6];
    }
    char* w = (char*)d_ws;
    float*    g    = (float*)(w);                   // 16,777,216 B
    unsigned* curs = (unsigned*)(w + 16777216);     //     65,536 B
    unsigned* csr  = (unsigned*)(w + 16842752);     //  2,097,152 B
    bf16*     h1   = (bf16*)(w + 18939904);         //  2,097,152 B
    bf16*     xo   = (bf16*)(w + 21037056);         //  1,048,576 B
    bf16*     h3   = (bf16*)(w + 22085632);         //  2,097,152 B
    bf16*     Bp   = (bf16*)(w + 24182784);         //    327,680 B
    bf16*     xyc  = (bf16*)(w + 24510464);         //  2,097,152 B
    float*    outp = (float*)d_out;

    hipMemsetAsync(curs, 0, NN*sizeof(unsigned), stream);
    k_setup<<<464, 256, 0, stream>>>(recv, send, curs, csr, rel, a,
                                     P[0], P[1], P[2], P[3], g,
                                     W[0], W[1], W[2], W[3], Bp,
                                     x, y, xyc);

    // conv1: xyc -> h1 (BN+relu)
    (k_conv<64,4,0,bf16>) <<<NN/16, 1024, 0, stream>>>(xyc, g + (size_t)0*NE*16, csr, curs,
        Bp + (size_t)0*8,     bb[0], bs[0], bo[0], bm[0], bv[0], nullptr, nullptr, h1);
    // conv2: h1 -> wei1 -> xo (AFF)
    (k_conv<64,2,1,bf16>) <<<NN/16, 1024, 0, stream>>>(h1, g + (size_t)1*NE*16, csr, curs,
        Bp + (size_t)8192*8,  bb[1], bs[1], bo[1], bm[1], bv[1], x, y, xo);
    // conv3: xo -> h3 (BN+relu)
    (k_conv<32,4,0,bf16>) <<<NN/16, 1024, 0, stream>>>(xo, g + (size_t)2*NE*16, csr, curs,
        Bp + (size_t)12288*8, bb[2], bs[2], bo[2], bm[2], bv[2], nullptr, nullptr, h3);
    // conv4: h3 -> wei2 -> out (AFF, f32)
    (k_conv<64,2,1,float>)<<<NN/16, 1024, 0, stream>>>(h3, g + (size_t)3*NE*16, csr, curs,
        Bp + (size_t)16384*8, bb[3], bs[3], bo[3], bm[3], bv[3], x, y, outp);
}